// Round 1
// baseline (596.980 us; speedup 1.0000x reference)
//
#include <hip/hip_runtime.h>

#define IN_SIZE 256
#define HIDDEN 16
#define OUT_SIZE 64

// ---------------- zero scratch ----------------
__global__ __launch_bounds__(256) void zero_kernel(float* __restrict__ a, long n) {
    long i = (long)blockIdx.x * blockDim.x + threadIdx.x;
    long stride = (long)gridDim.x * blockDim.x;
    for (; i < n; i += stride) a[i] = 0.0f;
}

// ---------------- H1 = X @ W1^T + b1  [n,16] ----------------
// block = 256 threads -> 16 nodes, thread t: node = blk*16 + t/16, h = t%16
__global__ __launch_bounds__(256) void dense1_kernel(
    const float* __restrict__ X, const float* __restrict__ W1,
    const float* __restrict__ b1, float* __restrict__ H1, int n) {
    __shared__ float w[HIDDEN * IN_SIZE];  // transposed: w[k*16 + h] = W1[h][k]
    for (int i = threadIdx.x; i < HIDDEN * IN_SIZE; i += 256) {
        int h = i >> 8;        // i / 256
        int k = i & 255;       // i % 256
        w[k * HIDDEN + h] = W1[i];
    }
    __syncthreads();
    int t = threadIdx.x;
    int node = blockIdx.x * 16 + (t >> 4);
    int h = t & 15;
    if (node >= n) return;
    const float4* xr = reinterpret_cast<const float4*>(X + (size_t)node * IN_SIZE);
    float acc = b1[h];
#pragma unroll 8
    for (int kk = 0; kk < IN_SIZE / 4; ++kk) {
        float4 x = xr[kk];  // 16 lanes share this address -> broadcast
        const float* wr = &w[(kk * 4) * HIDDEN + h];
        acc += x.x * wr[0 * HIDDEN] + x.y * wr[1 * HIDDEN] +
               x.z * wr[2 * HIDDEN] + x.w * wr[3 * HIDDEN];
    }
    H1[(size_t)node * HIDDEN + h] = acc;  // coalesced: flat index = blk*256 + t
}

// ---------------- Sout[r] += val * (relu?)(Hin[c])  [n,16] ----------------
// thread t: e = t/16, k = t%16. Optionally accumulates weighted degree.
__global__ __launch_bounds__(256) void spmm16_kernel(
    const int* __restrict__ row, const int* __restrict__ col,
    const float* __restrict__ val, const float* __restrict__ Hin,
    float* __restrict__ Sout, float* __restrict__ deg, long nedges, int relu_in) {
    long t = (long)blockIdx.x * 256 + threadIdx.x;
    long e = t >> 4;
    if (e >= nedges) return;
    int k = (int)(t & 15);
    int r = row[e];
    int c = col[e];
    float v = val[e];
    float x = Hin[(size_t)c * HIDDEN + k];
    if (relu_in) x = fmaxf(x, 0.0f);
    atomicAdd(&Sout[(size_t)r * HIDDEN + k], v * x);
    if (deg != nullptr && k == 0) atomicAdd(&deg[r], v);
}

// ---------------- out = relu(T @ W2^T + deg*b2)  [n,64] ----------------
// block = 256 -> 4 nodes, thread: node = blk*4 + t/64, o = t%64
__global__ __launch_bounds__(256) void dense2_kernel(
    const float* __restrict__ T, const float* __restrict__ deg,
    const float* __restrict__ W2, const float* __restrict__ b2,
    float* __restrict__ out, int n) {
    __shared__ float w[OUT_SIZE * HIDDEN];  // transposed: w[h*64 + o] = W2[o][h]
    for (int i = threadIdx.x; i < OUT_SIZE * HIDDEN; i += 256) {
        int o = i / HIDDEN;
        int h = i % HIDDEN;
        w[h * OUT_SIZE + o] = W2[i];
    }
    __syncthreads();
    int node = blockIdx.x * 4 + (threadIdx.x >> 6);
    int o = threadIdx.x & 63;
    if (node >= n) return;
    float acc = deg[node] * b2[o];
#pragma unroll
    for (int h = 0; h < HIDDEN; ++h)
        acc += T[(size_t)node * HIDDEN + h] * w[h * OUT_SIZE + o];
    out[(size_t)node * OUT_SIZE + o] = fmaxf(acc, 0.0f);
}

extern "C" void kernel_launch(void* const* d_in, const int* in_sizes, int n_in,
                              void* d_out, int out_size, void* d_ws, size_t ws_size,
                              hipStream_t stream) {
    const int*   index = (const int*)d_in[0];    // [2, nedges]
    const float* value = (const float*)d_in[1];  // [nedges]
    const float* X     = (const float*)d_in[4];  // [n, 256]
    const float* W1    = (const float*)d_in[5];  // [16, 256]
    const float* b1    = (const float*)d_in[6];  // [16]
    const float* W2    = (const float*)d_in[7];  // [64, 16]
    const float* b2    = (const float*)d_in[8];  // [64]
    float* out = (float*)d_out;

    long nedges = in_sizes[1];
    int  n      = in_sizes[4] / IN_SIZE;

    const int* row = index;
    const int* col = index + nedges;

    // workspace layout (floats): H1[n*16] | S1[n*16] | T[n*16] | deg[n]
    float* ws = (float*)d_ws;
    float* H1  = ws;
    float* S1  = H1 + (size_t)n * HIDDEN;
    float* T   = S1 + (size_t)n * HIDDEN;
    float* deg = T + (size_t)n * HIDDEN;

    // 1. zero accumulators (S1, T, deg are contiguous: n*33 floats)
    zero_kernel<<<2048, 256, 0, stream>>>(S1, (long)n * (2 * HIDDEN + 1));

    // 2. H1 = X @ W1^T + b1
    dense1_kernel<<<(n + 15) / 16, 256, 0, stream>>>(X, W1, b1, H1, n);

    // 3. S1 = spmm(H1), deg = weighted degree
    long thr1 = nedges * HIDDEN;
    spmm16_kernel<<<(thr1 + 255) / 256, 256, 0, stream>>>(
        row, col, value, H1, S1, deg, nedges, 0);

    // 4. T = spmm(relu(S1))
    spmm16_kernel<<<(thr1 + 255) / 256, 256, 0, stream>>>(
        row, col, value, S1, T, nullptr, nedges, 1);

    // 5. out = relu(T @ W2^T + deg*b2)
    dense2_kernel<<<(n + 3) / 4, 256, 0, stream>>>(T, deg, W2, b2, out, n);
}